// Round 7
// baseline (369.082 us; speedup 1.0000x reference)
//
#include <hip/hip_runtime.h>
#include <hip/hip_bf16.h>
#include <math.h>

#define B_   256
#define L_   196
#define ENC_ 2048
#define DEC_ 512
#define HID_ 512

typedef __attribute__((ext_vector_type(8))) short short8v;
typedef __attribute__((ext_vector_type(4))) short short4v;
typedef __attribute__((ext_vector_type(4))) float f32x4;

static __device__ __forceinline__ short f2bf(float x) {
    unsigned u = __float_as_uint(x);
    u += 0x7fffu + ((u >> 16) & 1u);   // round-to-nearest-even
    return (short)(u >> 16);
}

// ---------------------------------------------------------------------------
// Wf (f32 [512,2048]) -> bf16, stored PRE-SWIZZLED: within each row, 16B unit
// U holds original unit U ^ (n&7).  Then the GEMM can stage with linear
// global_load_lds and read LDS with the same XOR (T2, conflict-free).
// ---------------------------------------------------------------------------
__global__ __launch_bounds__(256) void kconvert(const float* __restrict__ Wf,
                                                short* __restrict__ wfbf) {
    int idx = (blockIdx.x * 256 + threadIdx.x) * 4;   // over 512*2048 = 1M elems
    int n  = idx >> 11;
    int e0 = idx & 2047;
    float4 f = *(const float4*)(Wf + idx);
    short4v h;
    h.x = f2bf(f.x); h.y = f2bf(f.y); h.z = f2bf(f.z); h.w = f2bf(f.w);
    int unit = (e0 >> 3) ^ (n & 7);
    int off  = n * 2048 + unit * 8 + (e0 & 7);
    *(short4v*)(wfbf + off) = h;
}

// ---------------------------------------------------------------------------
// hid_emb[b,h] = hidden[b,:] . Wh[h,:] + bh[h]     (256x512, K=512, fp32)
// ---------------------------------------------------------------------------
__global__ __launch_bounds__(512) void khid(const float* __restrict__ hidden,
                                            const float* __restrict__ Wh,
                                            const float* __restrict__ bh,
                                            float* __restrict__ hid_emb) {
    __shared__ float hs[8][512];
    int t = threadIdx.x;
    int bg = blockIdx.x * 8;
    #pragma unroll
    for (int i = 0; i < 8; ++i) hs[i][t] = hidden[(size_t)(bg + i) * 512 + t];
    __syncthreads();
    float acc[8] = {0.f,0.f,0.f,0.f,0.f,0.f,0.f,0.f};
    const float4* wrow = (const float4*)(Wh + (size_t)t * 512);
    #pragma unroll 4
    for (int d4 = 0; d4 < 128; ++d4) {
        float4 w = wrow[d4];
        int d = d4 * 4;
        #pragma unroll
        for (int i = 0; i < 8; ++i)
            acc[i] += w.x * hs[i][d] + w.y * hs[i][d+1] + w.z * hs[i][d+2] + w.w * hs[i][d+3];
    }
    float bhv = bh[t];
    #pragma unroll
    for (int i = 0; i < 8; ++i)
        hid_emb[(size_t)(bg + i) * 512 + t] = acc[i] + bhv;
}

// ---------------------------------------------------------------------------
// Fused score GEMM v4: 64M x 512N tile, BK=64, 512 threads / 8 waves,
// wave = 64x64 sub-tile.  T3 2-phase double-buffered pipeline:
//   per iter: issue STAGE(k+1) (A f32 loads -> regs, B global_load_lds)
//             BEFORE compute(k); convert+ds_write A(k+1) AFTER the MFMAs
//             (T14 write-late); one implicit vmcnt(0)+barrier per K-step.
// The ~900cy HBM latency of the A loads is hidden under compute(k).
// LDS 146 KB -> 1 block/CU (occupancy proven non-binding in R6).
// Index formulas and numerics identical to the verified v3.
// ---------------------------------------------------------------------------
__global__ __launch_bounds__(512, 2) void kscore(
    const float* __restrict__ feat, const short* __restrict__ wfbf,
    const float* __restrict__ bf, const float* __restrict__ hid_emb,
    const float* __restrict__ We, const float* __restrict__ be,
    float* __restrict__ score)
{
    __shared__ short lds_b[2 * 512 * 64];   // 2 x 64 KB, swizzled [n][k]
    __shared__ short lds_a[2 * 64 * 64];    // 2 x  8 KB, swizzled [r][k]
    __shared__ float score_s[8][64];

    const int tid  = threadIdx.x;
    const int wave = tid >> 6;
    const int lane = tid & 63;
    const int g    = lane >> 4;
    const int c    = lane & 15;
    const int m0   = blockIdx.x * 64;

    // ---- fixed per-thread staging geometry ----
    const int ch0 = tid,       r0 = ch0 >> 4, c40 = ch0 & 15;
    const int ch1 = tid + 512, r1 = ch1 >> 4, c41 = ch1 & 15;
    const float* gA0 = feat + (size_t)(m0 + r0) * ENC_ + c40 * 4;
    const float* gA1 = feat + (size_t)(m0 + r1) * ENC_ + c41 * 4;
    const int boff0 = r0 * 128 + (((c40 >> 1) ^ (r0 & 7)) << 4) + (c40 & 1) * 8;
    const int boff1 = r1 * 128 + (((c41 >> 1) ^ (r1 & 7)) << 4) + (c41 & 1) * 8;

    f32x4 acc[4][4];
    #pragma unroll
    for (int i = 0; i < 4; ++i)
        #pragma unroll
        for (int j = 0; j < 4; ++j)
            acc[i][j] = (f32x4)0.f;

    // ---- prologue: stage K-tile 0 into buffer 0 ----
    {
        float4 fa = *(const float4*)(gA0);
        float4 fb = *(const float4*)(gA1);
        #pragma unroll
        for (int j = 0; j < 8; ++j) {
            int ubase = j * 512 + wave * 64;          // wave-uniform unit base
            int ulin  = ubase + lane;
            int n = ulin >> 3, u = ulin & 7;
            const short* gp = wfbf + (size_t)n * ENC_ + u * 8;
            short* lp = lds_b + (size_t)ubase * 8;
            __builtin_amdgcn_global_load_lds(
                (const __attribute__((address_space(1))) void*)gp,
                (__attribute__((address_space(3))) void*)lp, 16, 0, 0);
        }
        short4v h0, h1;
        h0.x = f2bf(fa.x); h0.y = f2bf(fa.y); h0.z = f2bf(fa.z); h0.w = f2bf(fa.w);
        h1.x = f2bf(fb.x); h1.y = f2bf(fb.y); h1.z = f2bf(fb.z); h1.w = f2bf(fb.w);
        *(short4v*)((char*)lds_a + boff0) = h0;
        *(short4v*)((char*)lds_a + boff1) = h1;
    }
    __syncthreads();

    int cur = 0;
    for (int kt = 0; kt < 32; ++kt) {
        const int kn = (kt + 1) * 64;                 // next K-tile origin
        float4 fa, fb;
        // ---- issue STAGE(k+1) before compute(k) ----
        if (kt < 31) {
            fa = *(const float4*)(gA0 + kn);
            fb = *(const float4*)(gA1 + kn);
            short* bbase = lds_b + (size_t)(cur ^ 1) * 32768;
            #pragma unroll
            for (int j = 0; j < 8; ++j) {
                int ubase = j * 512 + wave * 64;
                int ulin  = ubase + lane;
                int n = ulin >> 3, u = ulin & 7;
                const short* gp = wfbf + (size_t)n * ENC_ + kn + u * 8;
                short* lp = bbase + (size_t)ubase * 8;
                __builtin_amdgcn_global_load_lds(
                    (const __attribute__((address_space(1))) void*)gp,
                    (__attribute__((address_space(3))) void*)lp, 16, 0, 0);
            }
        }
        // ---- compute(k) from buffer cur ----
        const char* la = (const char*)lds_a + cur * 8192;
        const char* lb = (const char*)lds_b + cur * 65536;
        #pragma unroll
        for (int kf = 0; kf < 2; ++kf) {
            short8v af[4], bq[4];
            #pragma unroll
            for (int mi = 0; mi < 4; ++mi) {
                int row = mi * 16 + c;                 // A: row = lane&15
                int un  = (kf * 4 + g) ^ (row & 7);
                af[mi] = *(const short8v*)(la + row * 128 + un * 16);
            }
            #pragma unroll
            for (int ni = 0; ni < 4; ++ni) {
                int n  = wave * 64 + ni * 16 + c;      // B: col = lane&15
                int un = (kf * 4 + g) ^ (n & 7);
                bq[ni] = *(const short8v*)(lb + n * 128 + un * 16);
            }
            #pragma unroll
            for (int mi = 0; mi < 4; ++mi)
                #pragma unroll
                for (int ni = 0; ni < 4; ++ni)
                    acc[mi][ni] = __builtin_amdgcn_mfma_f32_16x16x32_bf16(
                        af[mi], bq[ni], acc[mi][ni], 0, 0, 0);
        }
        // ---- write-late: convert A(k+1) and store into buffer cur^1 ----
        if (kt < 31) {
            short4v h0, h1;
            h0.x = f2bf(fa.x); h0.y = f2bf(fa.y); h0.z = f2bf(fa.z); h0.w = f2bf(fa.w);
            h1.x = f2bf(fb.x); h1.y = f2bf(fb.y); h1.z = f2bf(fb.z); h1.w = f2bf(fb.w);
            char* wa = (char*)lds_a + (cur ^ 1) * 8192;
            *(short4v*)(wa + boff0) = h0;
            *(short4v*)(wa + boff1) = h1;
        }
        __syncthreads();
        cur ^= 1;
    }

    // ---- fused epilogue: +bf +hid_emb, relu, dot We, reduce over n ----
    float wev[4], bfv[4];
    #pragma unroll
    for (int ni = 0; ni < 4; ++ni) {
        int n = wave * 64 + ni * 16 + c;
        wev[ni] = We[n];
        bfv[ni] = bf[n];
    }
    #pragma unroll
    for (int mi = 0; mi < 4; ++mi) {
        float part[4] = {0.f, 0.f, 0.f, 0.f};
        #pragma unroll
        for (int j = 0; j < 4; ++j) {
            int row  = mi * 16 + g * 4 + j;            // C/D: row=(lane>>4)*4+reg
            int bidx = (m0 + row) / 196;
            const float* hrow = hid_emb + (size_t)bidx * 512;
            #pragma unroll
            for (int ni = 0; ni < 4; ++ni) {
                int n = wave * 64 + ni * 16 + c;
                float v = acc[mi][ni][j] + bfv[ni] + hrow[n];
                v = fmaxf(v, 0.f);
                part[j] += v * wev[ni];
            }
        }
        #pragma unroll
        for (int j = 0; j < 4; ++j) {
            float p = part[j];
            p += __shfl_xor(p, 1, 16);
            p += __shfl_xor(p, 2, 16);
            p += __shfl_xor(p, 4, 16);
            p += __shfl_xor(p, 8, 16);
            if (c == 0) score_s[wave][mi * 16 + g * 4 + j] = p;
        }
    }
    __syncthreads();
    if (tid < 64) {
        float s = be[0];
        #pragma unroll
        for (int w = 0; w < 8; ++w) s += score_s[w][tid];
        score[m0 + tid] = s;
    }
}

// ---------------------------------------------------------------------------
// Softmax over L=196 + output[b,e] = sum_l w[l] * feature[b,l,e].
// 2 blocks per b (each does 1024 of the 2048 columns; both recompute softmax).
// ---------------------------------------------------------------------------
__global__ __launch_bounds__(256) void kout(
    const float* __restrict__ score, const float* __restrict__ feat,
    float* __restrict__ out_o, float* __restrict__ out_w)
{
    __shared__ float wbuf[196];
    __shared__ float red[8];
    int t    = threadIdx.x;
    int b    = blockIdx.x >> 1;
    int half = blockIdx.x & 1;
    int w    = t >> 6, lane = t & 63;

    float s = (t < 196) ? score[b * 196 + t] : -1e30f;
    float m = s;
    #pragma unroll
    for (int off = 32; off >= 1; off >>= 1) m = fmaxf(m, __shfl_xor(m, off, 64));
    if (lane == 0) red[w] = m;
    __syncthreads();
    m = fmaxf(fmaxf(red[0], red[1]), fmaxf(red[2], red[3]));
    float e = (t < 196) ? __expf(s - m) : 0.f;
    float sum = e;
    #pragma unroll
    for (int off = 32; off >= 1; off >>= 1) sum += __shfl_xor(sum, off, 64);
    if (lane == 0) red[4 + w] = sum;
    __syncthreads();
    sum = red[4] + red[5] + red[6] + red[7];
    float wt = e / sum;
    if (t < 196) {
        wbuf[t] = wt;
        if (half == 0) out_w[b * 196 + t] = wt;
    }
    __syncthreads();

    int e0 = half * 1024 + t * 4;
    float4 acc = make_float4(0.f, 0.f, 0.f, 0.f);
    const float* fb = feat + (size_t)b * L_ * ENC_ + e0;
    #pragma unroll 4
    for (int l = 0; l < 196; ++l) {
        float4 v = *(const float4*)(fb + (size_t)l * ENC_);
        float wl = wbuf[l];
        acc.x += wl * v.x; acc.y += wl * v.y; acc.z += wl * v.z; acc.w += wl * v.w;
    }
    *(float4*)(out_o + (size_t)b * ENC_ + e0) = acc;
}

extern "C" void kernel_launch(void* const* d_in, const int* in_sizes, int n_in,
                              void* d_out, int out_size, void* d_ws, size_t ws_size,
                              hipStream_t stream) {
    (void)in_sizes; (void)n_in; (void)out_size; (void)ws_size;
    const float* feature = (const float*)d_in[0];
    const float* hidden  = (const float*)d_in[1];
    const float* Wf      = (const float*)d_in[2];
    const float* bf      = (const float*)d_in[3];
    const float* Wh      = (const float*)d_in[4];
    const float* bh      = (const float*)d_in[5];
    const float* We      = (const float*)d_in[6];
    const float* be      = (const float*)d_in[7];

    char* ws = (char*)d_ws;
    short* wfbf    = (short*)ws;                               // 2 MB
    float* hid_emb = (float*)(ws + (2u << 20));                // 512 KB
    float* score   = (float*)(ws + (2u << 20) + (512u << 10)); // 200 KB

    float* out_o = (float*)d_out;                 // [256,2048]
    float* out_w = out_o + (size_t)B_ * ENC_;     // [256,196]

    kconvert<<<dim3(1024), dim3(256), 0, stream>>>(Wf, wfbf);
    khid<<<dim3(32), dim3(512), 0, stream>>>(hidden, Wh, bh, hid_emb);
    kscore<<<dim3(784), dim3(512), 0, stream>>>(feature, wfbf, bf, hid_emb, We, be, score);
    kout<<<dim3(512), dim3(256), 0, stream>>>(score, feature, (float*)d_out, out_w);
}

// Round 8
// 323.315 us; speedup vs baseline: 1.1416x; 1.1416x over previous
//
#include <hip/hip_runtime.h>
#include <hip/hip_bf16.h>
#include <math.h>

#define B_   256
#define L_   196
#define ENC_ 2048
#define DEC_ 512
#define HID_ 512

typedef __attribute__((ext_vector_type(8))) short short8v;
typedef __attribute__((ext_vector_type(4))) short short4v;
typedef __attribute__((ext_vector_type(4))) float f32x4;

static __device__ __forceinline__ short f2bf(float x) {
    unsigned u = __float_as_uint(x);
    u += 0x7fffu + ((u >> 16) & 1u);   // round-to-nearest-even
    return (short)(u >> 16);
}

// ---------------------------------------------------------------------------
// Wf (f32 [512,2048]) -> bf16, stored PRE-SWIZZLED: within each row, 16B unit
// U holds original unit U ^ (n&7).
// ---------------------------------------------------------------------------
__global__ __launch_bounds__(256) void kconvert(const float* __restrict__ Wf,
                                                short* __restrict__ wfbf) {
    int idx = (blockIdx.x * 256 + threadIdx.x) * 4;   // over 512*2048 = 1M elems
    int n  = idx >> 11;
    int e0 = idx & 2047;
    float4 f = *(const float4*)(Wf + idx);
    short4v h;
    h.x = f2bf(f.x); h.y = f2bf(f.y); h.z = f2bf(f.z); h.w = f2bf(f.w);
    int unit = (e0 >> 3) ^ (n & 7);
    int off  = n * 2048 + unit * 8 + (e0 & 7);
    *(short4v*)(wfbf + off) = h;
}

// ---------------------------------------------------------------------------
// hid_emb[b,h] = hidden[b,:] . Wh[h,:] + bh[h]     (256x512, K=512, fp32)
// ---------------------------------------------------------------------------
__global__ __launch_bounds__(512) void khid(const float* __restrict__ hidden,
                                            const float* __restrict__ Wh,
                                            const float* __restrict__ bh,
                                            float* __restrict__ hid_emb) {
    __shared__ float hs[8][512];
    int t = threadIdx.x;
    int bg = blockIdx.x * 8;
    #pragma unroll
    for (int i = 0; i < 8; ++i) hs[i][t] = hidden[(size_t)(bg + i) * 512 + t];
    __syncthreads();
    float acc[8] = {0.f,0.f,0.f,0.f,0.f,0.f,0.f,0.f};
    const float4* wrow = (const float4*)(Wh + (size_t)t * 512);
    #pragma unroll 4
    for (int d4 = 0; d4 < 128; ++d4) {
        float4 w = wrow[d4];
        int d = d4 * 4;
        #pragma unroll
        for (int i = 0; i < 8; ++i)
            acc[i] += w.x * hs[i][d] + w.y * hs[i][d+1] + w.z * hs[i][d+2] + w.w * hs[i][d+3];
    }
    float bhv = bh[t];
    #pragma unroll
    for (int i = 0; i < 8; ++i)
        hid_emb[(size_t)(bg + i) * 512 + t] = acc[i] + bhv;
}

// ---------------------------------------------------------------------------
// Fused score GEMM v5: 64M x 512N tile, BK=64, 512 threads / 8 waves,
// double-buffered LDS, RAW s_barrier + COUNTED vmcnt (T4):
//   per iter k: issue B(k+1) [8 gload_lds] + A(k+2) [2 f32 loads],
//               compute(k), convert+ds_write A(k+1) (compiler waits
//               vmcnt(10) for it automatically), then
//               s_waitcnt vmcnt(2) lgkmcnt(0)  <- waits B(k+1) only,
//               A(k+2) stays in flight across the barrier.
// One raw s_barrier per iter; dbuf makes it race-free (writes always go
// to the non-current buffer).  sched_barrier(0) pins memory ops around
// the barrier (rule #18).  Tail (k=30,31) peeled for constant immediates.
// ---------------------------------------------------------------------------
__global__ __launch_bounds__(512, 2) void kscore(
    const float* __restrict__ feat, const short* __restrict__ wfbf,
    const float* __restrict__ bf, const float* __restrict__ hid_emb,
    const float* __restrict__ We, const float* __restrict__ be,
    float* __restrict__ score)
{
    __shared__ short lds_b[2 * 512 * 64];   // 2 x 64 KB, swizzled [n][k]
    __shared__ short lds_a[2 * 64 * 64];    // 2 x  8 KB, swizzled [r][k]
    __shared__ float score_s[8][64];

    const int tid  = threadIdx.x;
    const int wave = tid >> 6;
    const int lane = tid & 63;
    const int g    = lane >> 4;
    const int c    = lane & 15;
    const int m0   = blockIdx.x * 64;

    // ---- fixed per-thread A staging geometry ----
    const int ch0 = tid,       r0 = ch0 >> 4, c40 = ch0 & 15;
    const int ch1 = tid + 512, r1 = ch1 >> 4, c41 = ch1 & 15;
    const float* gA0 = feat + (size_t)(m0 + r0) * ENC_ + c40 * 4;
    const float* gA1 = feat + (size_t)(m0 + r1) * ENC_ + c41 * 4;
    const int boff0 = r0 * 128 + (((c40 >> 1) ^ (r0 & 7)) << 4) + (c40 & 1) * 8;
    const int boff1 = r1 * 128 + (((c41 >> 1) ^ (r1 & 7)) << 4) + (c41 & 1) * 8;

    f32x4 acc[4][4];
    #pragma unroll
    for (int i = 0; i < 4; ++i)
        #pragma unroll
        for (int j = 0; j < 4; ++j)
            acc[i][j] = (f32x4)0.f;

    // ---- B staging helper (macro keeps gload_lds size literal) ----
#define STAGE_B(K0, BUF)                                                      \
    {                                                                         \
        short* bbase = lds_b + (size_t)(BUF) * 32768;                         \
        _Pragma("unroll")                                                     \
        for (int j = 0; j < 8; ++j) {                                         \
            int ubase = j * 512 + wave * 64;                                  \
            int ulin  = ubase + lane;                                         \
            int n = ulin >> 3, u = ulin & 7;                                  \
            const short* gp = wfbf + (size_t)n * ENC_ + (K0) + u * 8;         \
            short* lp = bbase + (size_t)ubase * 8;                            \
            __builtin_amdgcn_global_load_lds(                                 \
                (const __attribute__((address_space(1))) void*)gp,            \
                (__attribute__((address_space(3))) void*)lp, 16, 0, 0);       \
        }                                                                     \
    }

#define COMPUTE_TILE(BUF)                                                     \
    {                                                                         \
        const char* la = (const char*)lds_a + (BUF) * 8192;                   \
        const char* lb = (const char*)lds_b + (BUF) * 65536;                  \
        _Pragma("unroll")                                                     \
        for (int kf = 0; kf < 2; ++kf) {                                      \
            short8v af[4], bq[4];                                             \
            _Pragma("unroll")                                                 \
            for (int mi = 0; mi < 4; ++mi) {                                  \
                int row = mi * 16 + c;                                        \
                int un  = (kf * 4 + g) ^ (row & 7);                           \
                af[mi] = *(const short8v*)(la + row * 128 + un * 16);         \
            }                                                                 \
            _Pragma("unroll")                                                 \
            for (int ni = 0; ni < 4; ++ni) {                                  \
                int n  = wave * 64 + ni * 16 + c;                             \
                int un = (kf * 4 + g) ^ (n & 7);                              \
                bq[ni] = *(const short8v*)(lb + n * 128 + un * 16);           \
            }                                                                 \
            _Pragma("unroll")                                                 \
            for (int mi = 0; mi < 4; ++mi)                                    \
                _Pragma("unroll")                                             \
                for (int ni = 0; ni < 4; ++ni)                                \
                    acc[mi][ni] = __builtin_amdgcn_mfma_f32_16x16x32_bf16(    \
                        af[mi], bq[ni], acc[mi][ni], 0, 0, 0);                \
        }                                                                     \
    }

#define WRITE_A(FA, FB, BUF)                                                  \
    {                                                                         \
        short4v h0, h1;                                                       \
        h0.x = f2bf((FA).x); h0.y = f2bf((FA).y);                             \
        h0.z = f2bf((FA).z); h0.w = f2bf((FA).w);                             \
        h1.x = f2bf((FB).x); h1.y = f2bf((FB).y);                             \
        h1.z = f2bf((FB).z); h1.w = f2bf((FB).w);                             \
        char* wa = (char*)lds_a + (BUF) * 8192;                               \
        *(short4v*)(wa + boff0) = h0;                                         \
        *(short4v*)(wa + boff1) = h1;                                         \
    }

#define BAR_COUNTED(N)                                                        \
    asm volatile("s_waitcnt vmcnt(" #N ") lgkmcnt(0)" ::: "memory");          \
    __builtin_amdgcn_sched_barrier(0);                                        \
    __builtin_amdgcn_s_barrier();                                             \
    __builtin_amdgcn_sched_barrier(0);

    // ---- prologue ----
    float4 fa_cur0 = *(const float4*)(gA0);          // A(0)  [2 vmem]
    float4 fa_cur1 = *(const float4*)(gA1);
    STAGE_B(0, 0)                                    // B(0)  [8 vmem]
    float4 fa_nxt0 = *(const float4*)(gA0 + 64);     // A(1)  [2 vmem]
    float4 fa_nxt1 = *(const float4*)(gA1 + 64);
    WRITE_A(fa_cur0, fa_cur1, 0)                     // compiler waits vmcnt(10)
    fa_cur0 = fa_nxt0; fa_cur1 = fa_nxt1;
    BAR_COUNTED(2)                                   // B(0) done; A(1) flying

    // ---- main loop: k = 0..29 ----
    for (int kt = 0; kt < 30; ++kt) {
        const int pcur = kt & 1;
        const int kb = (kt + 1) * 64;                // B prefetch origin
        const int ka = (kt + 2) * 64;                // A prefetch origin
        STAGE_B(kb, pcur ^ 1)                        // B(k+1) [8 vmem]
        fa_nxt0 = *(const float4*)(gA0 + ka);        // A(k+2) [2 vmem]
        fa_nxt1 = *(const float4*)(gA1 + ka);
        COMPUTE_TILE(pcur)
        WRITE_A(fa_cur0, fa_cur1, pcur ^ 1)          // A(k+1); waits vmcnt(10)
        fa_cur0 = fa_nxt0; fa_cur1 = fa_nxt1;
        BAR_COUNTED(2)                               // B(k+1) done; A(k+2) flying
    }
    // ---- peel k = 30 ----
    STAGE_B(31 * 64, 1)                              // B(31)
    COMPUTE_TILE(0)
    WRITE_A(fa_cur0, fa_cur1, 1)                     // A(31)
    BAR_COUNTED(0)                                   // drain everything
    // ---- peel k = 31 ----
    COMPUTE_TILE(1)

#undef STAGE_B
#undef COMPUTE_TILE
#undef WRITE_A
#undef BAR_COUNTED

    // ---- fused epilogue: +bf +hid_emb, relu, dot We, reduce over n ----
    float wev[4], bfv[4];
    #pragma unroll
    for (int ni = 0; ni < 4; ++ni) {
        int n = wave * 64 + ni * 16 + c;
        wev[ni] = We[n];
        bfv[ni] = bf[n];
    }
    #pragma unroll
    for (int mi = 0; mi < 4; ++mi) {
        float part[4] = {0.f, 0.f, 0.f, 0.f};
        #pragma unroll
        for (int j = 0; j < 4; ++j) {
            int row  = mi * 16 + g * 4 + j;            // C/D: row=(lane>>4)*4+reg
            int bidx = (m0 + row) / 196;
            const float* hrow = hid_emb + (size_t)bidx * 512;
            #pragma unroll
            for (int ni = 0; ni < 4; ++ni) {
                int n = wave * 64 + ni * 16 + c;
                float v = acc[mi][ni][j] + bfv[ni] + hrow[n];
                v = fmaxf(v, 0.f);
                part[j] += v * wev[ni];
            }
        }
        #pragma unroll
        for (int j = 0; j < 4; ++j) {
            float p = part[j];
            p += __shfl_xor(p, 1, 16);
            p += __shfl_xor(p, 2, 16);
            p += __shfl_xor(p, 4, 16);
            p += __shfl_xor(p, 8, 16);
            if (c == 0) score_s[wave][mi * 16 + g * 4 + j] = p;
        }
    }
    __syncthreads();
    if (tid < 64) {
        float s = be[0];
        #pragma unroll
        for (int w = 0; w < 8; ++w) s += score_s[w][tid];
        score[m0 + tid] = s;
    }
}

// ---------------------------------------------------------------------------
// Softmax over L=196 + output[b,e] = sum_l w[l] * feature[b,l,e].
// ---------------------------------------------------------------------------
__global__ __launch_bounds__(256) void kout(
    const float* __restrict__ score, const float* __restrict__ feat,
    float* __restrict__ out_o, float* __restrict__ out_w)
{
    __shared__ float wbuf[196];
    __shared__ float red[8];
    int t    = threadIdx.x;
    int b    = blockIdx.x >> 1;
    int half = blockIdx.x & 1;
    int w    = t >> 6, lane = t & 63;

    float s = (t < 196) ? score[b * 196 + t] : -1e30f;
    float m = s;
    #pragma unroll
    for (int off = 32; off >= 1; off >>= 1) m = fmaxf(m, __shfl_xor(m, off, 64));
    if (lane == 0) red[w] = m;
    __syncthreads();
    m = fmaxf(fmaxf(red[0], red[1]), fmaxf(red[2], red[3]));
    float e = (t < 196) ? __expf(s - m) : 0.f;
    float sum = e;
    #pragma unroll
    for (int off = 32; off >= 1; off >>= 1) sum += __shfl_xor(sum, off, 64);
    if (lane == 0) red[4 + w] = sum;
    __syncthreads();
    sum = red[4] + red[5] + red[6] + red[7];
    float wt = e / sum;
    if (t < 196) {
        wbuf[t] = wt;
        if (half == 0) out_w[b * 196 + t] = wt;
    }
    __syncthreads();

    int e0 = half * 1024 + t * 4;
    float4 acc = make_float4(0.f, 0.f, 0.f, 0.f);
    const float* fb = feat + (size_t)b * L_ * ENC_ + e0;
    #pragma unroll 4
    for (int l = 0; l < 196; ++l) {
        float4 v = *(const float4*)(fb + (size_t)l * ENC_);
        float wl = wbuf[l];
        acc.x += wl * v.x; acc.y += wl * v.y; acc.z += wl * v.z; acc.w += wl * v.w;
    }
    *(float4*)(out_o + (size_t)b * ENC_ + e0) = acc;
}

extern "C" void kernel_launch(void* const* d_in, const int* in_sizes, int n_in,
                              void* d_out, int out_size, void* d_ws, size_t ws_size,
                              hipStream_t stream) {
    (void)in_sizes; (void)n_in; (void)out_size; (void)ws_size;
    const float* feature = (const float*)d_in[0];
    const float* hidden  = (const float*)d_in[1];
    const float* Wf      = (const float*)d_in[2];
    const float* bf      = (const float*)d_in[3];
    const float* Wh      = (const float*)d_in[4];
    const float* bh      = (const float*)d_in[5];
    const float* We      = (const float*)d_in[6];
    const float* be      = (const float*)d_in[7];

    char* ws = (char*)d_ws;
    short* wfbf    = (short*)ws;                               // 2 MB
    float* hid_emb = (float*)(ws + (2u << 20));                // 512 KB
    float* score   = (float*)(ws + (2u << 20) + (512u << 10)); // 200 KB

    float* out_o = (float*)d_out;                 // [256,2048]
    float* out_w = out_o + (size_t)B_ * ENC_;     // [256,196]

    kconvert<<<dim3(1024), dim3(256), 0, stream>>>(Wf, wfbf);
    khid<<<dim3(32), dim3(512), 0, stream>>>(hidden, Wh, bh, hid_emb);
    kscore<<<dim3(784), dim3(512), 0, stream>>>(feature, wfbf, bf, hid_emb, We, be, score);
    kout<<<dim3(512), dim3(256), 0, stream>>>(score, feature, (float*)d_out, out_w);
}

// Round 9
// 318.784 us; speedup vs baseline: 1.1578x; 1.0142x over previous
//
#include <hip/hip_runtime.h>
#include <hip/hip_bf16.h>
#include <math.h>

#define B_   256
#define L_   196
#define ENC_ 2048
#define DEC_ 512
#define HID_ 512

typedef __attribute__((ext_vector_type(8))) short short8v;
typedef __attribute__((ext_vector_type(4))) short short4v;
typedef __attribute__((ext_vector_type(4))) float f32x4;

static __device__ __forceinline__ short f2bf(float x) {
    unsigned u = __float_as_uint(x);
    u += 0x7fffu + ((u >> 16) & 1u);   // round-to-nearest-even
    return (short)(u >> 16);
}

// ---------------------------------------------------------------------------
// Wf (f32 [512,2048]) -> bf16, PRE-SWIZZLED for BK=32 tiles: within each
// 64B (4-unit) K-tile segment of row n, physical unit = logical ^ ((n>>1)&3).
// 2-way max bank aliasing on all LDS reads (free per m136).
// ---------------------------------------------------------------------------
__global__ __launch_bounds__(256) void kconvert(const float* __restrict__ Wf,
                                                short* __restrict__ wfbf) {
    int idx = (blockIdx.x * 256 + threadIdx.x) * 4;   // over 512*2048 = 1M elems
    int n  = idx >> 11;
    int e0 = idx & 2047;
    float4 f = *(const float4*)(Wf + idx);
    short4v h;
    h.x = f2bf(f.x); h.y = f2bf(f.y); h.z = f2bf(f.z); h.w = f2bf(f.w);
    int tile = e0 >> 5;                      // 32-elem K-tile within row
    int lu   = (e0 >> 3) & 3;                // logical 8-elem unit in tile
    int pu   = lu ^ ((n >> 1) & 3);          // physical unit (swizzled)
    int off  = n * 2048 + tile * 32 + pu * 8 + (e0 & 7);
    *(short4v*)(wfbf + off) = h;
}

// ---------------------------------------------------------------------------
// hid_emb[b,h] = hidden[b,:] . Wh[h,:] + bh[h]     (256x512, K=512, fp32)
// ---------------------------------------------------------------------------
__global__ __launch_bounds__(512) void khid(const float* __restrict__ hidden,
                                            const float* __restrict__ Wh,
                                            const float* __restrict__ bh,
                                            float* __restrict__ hid_emb) {
    __shared__ float hs[8][512];
    int t = threadIdx.x;
    int bg = blockIdx.x * 8;
    #pragma unroll
    for (int i = 0; i < 8; ++i) hs[i][t] = hidden[(size_t)(bg + i) * 512 + t];
    __syncthreads();
    float acc[8] = {0.f,0.f,0.f,0.f,0.f,0.f,0.f,0.f};
    const float4* wrow = (const float4*)(Wh + (size_t)t * 512);
    #pragma unroll 4
    for (int d4 = 0; d4 < 128; ++d4) {
        float4 w = wrow[d4];
        int d = d4 * 4;
        #pragma unroll
        for (int i = 0; i < 8; ++i)
            acc[i] += w.x * hs[i][d] + w.y * hs[i][d+1] + w.z * hs[i][d+2] + w.w * hs[i][d+3];
    }
    float bhv = bh[t];
    #pragma unroll
    for (int i = 0; i < 8; ++i)
        hid_emb[(size_t)(bg + i) * 512 + t] = acc[i] + bhv;
}

// ---------------------------------------------------------------------------
// Fused score GEMM v6: 64M x 512N tile, BK=32, 512 threads / 8 waves,
// wave = 64x64 sub-tile.  Double-buffered LDS (74 KB -> 2 blocks/CU) +
// counted vmcnt (T4): per iter issue B(k+1) [4 gload_lds] + A(k+2) [1 f32x4],
// compute(k) [4 af + 4 bq ds_read_b128, 16 MFMA], convert+write A(k+1)
// (compiler auto-waits vmcnt(5)), then s_waitcnt vmcnt(1) + s_barrier:
// B(k+1) complete, A(k+2) rides across the barrier.  64 iters, tail peeled.
// Swizzle for 64B rows: physical unit = logical ^ ((row>>1)&3)  (2-way max).
// ---------------------------------------------------------------------------
__global__ __launch_bounds__(512, 4) void kscore(
    const float* __restrict__ feat, const short* __restrict__ wfbf,
    const float* __restrict__ bf, const float* __restrict__ hid_emb,
    const float* __restrict__ We, const float* __restrict__ be,
    float* __restrict__ score)
{
    __shared__ short lds_b[2 * 512 * 32];   // 2 x 32 KB, swizzled [n][k32]
    __shared__ short lds_a[2 * 64 * 32];    // 2 x  4 KB, swizzled [r][k32]
    __shared__ float score_s[8][64];

    const int tid  = threadIdx.x;
    const int wave = tid >> 6;
    const int lane = tid & 63;
    const int g    = lane >> 4;
    const int c    = lane & 15;
    const int m0   = blockIdx.x * 64;

    // ---- per-thread A staging geometry: row r = tid>>3, 4 floats at c4*4 ----
    const int r_a  = tid >> 3;
    const int c4   = tid & 7;
    const float* gA = feat + (size_t)(m0 + r_a) * ENC_ + c4 * 4;
    const int boffA = r_a * 64 + (((c4 >> 1) ^ ((r_a >> 1) & 3)) << 4) + (c4 & 1) * 8;

    f32x4 acc[4][4];
    #pragma unroll
    for (int i = 0; i < 4; ++i)
        #pragma unroll
        for (int j = 0; j < 4; ++j)
            acc[i][j] = (f32x4)0.f;

#define STAGE_B(K0, BUF)                                                      \
    {                                                                         \
        short* bbase = lds_b + (size_t)(BUF) * 16384;                         \
        _Pragma("unroll")                                                     \
        for (int j = 0; j < 4; ++j) {                                         \
            int ubase = j * 512 + wave * 64;       /* wave-uniform unit base */\
            int ulin  = ubase + lane;              /* 2048 units total      */\
            int n = ulin >> 2, u = ulin & 3;                                  \
            const short* gp = wfbf + (size_t)n * ENC_ + (K0) + u * 8;         \
            short* lp = bbase + (size_t)ubase * 8;                            \
            __builtin_amdgcn_global_load_lds(                                 \
                (const __attribute__((address_space(1))) void*)gp,            \
                (__attribute__((address_space(3))) void*)lp, 16, 0, 0);       \
        }                                                                     \
    }

#define COMPUTE_TILE(BUF)                                                     \
    {                                                                         \
        const char* la = (const char*)lds_a + (BUF) * 4096;                   \
        const char* lb = (const char*)lds_b + (BUF) * 32768;                  \
        short8v af[4], bq[4];                                                 \
        _Pragma("unroll")                                                     \
        for (int mi = 0; mi < 4; ++mi) {                                      \
            int row = mi * 16 + c;                                            \
            int un  = g ^ ((row >> 1) & 3);                                   \
            af[mi] = *(const short8v*)(la + row * 64 + un * 16);              \
        }                                                                     \
        _Pragma("unroll")                                                     \
        for (int ni = 0; ni < 4; ++ni) {                                      \
            int n  = wave * 64 + ni * 16 + c;                                 \
            int un = g ^ ((n >> 1) & 3);                                      \
            bq[ni] = *(const short8v*)(lb + n * 64 + un * 16);                \
        }                                                                     \
        _Pragma("unroll")                                                     \
        for (int mi = 0; mi < 4; ++mi)                                        \
            _Pragma("unroll")                                                 \
            for (int ni = 0; ni < 4; ++ni)                                    \
                acc[mi][ni] = __builtin_amdgcn_mfma_f32_16x16x32_bf16(        \
                    af[mi], bq[ni], acc[mi][ni], 0, 0, 0);                    \
    }

#define WRITE_A(FA, BUF)                                                      \
    {                                                                         \
        short4v h0;                                                           \
        h0.x = f2bf((FA).x); h0.y = f2bf((FA).y);                             \
        h0.z = f2bf((FA).z); h0.w = f2bf((FA).w);                             \
        char* wa = (char*)lds_a + (BUF) * 4096;                               \
        *(short4v*)(wa + boffA) = h0;                                         \
    }

#define BAR_COUNTED(N)                                                        \
    asm volatile("s_waitcnt vmcnt(" #N ") lgkmcnt(0)" ::: "memory");          \
    __builtin_amdgcn_sched_barrier(0);                                        \
    __builtin_amdgcn_s_barrier();                                             \
    __builtin_amdgcn_sched_barrier(0);

    // ---- prologue: A(0), B(0), A(1); write A(0); barrier with A(1) flying ----
    float4 fa_cur = *(const float4*)(gA);            // A(0)
    STAGE_B(0, 0)                                    // B(0) [4 vmem]
    float4 fa_nxt = *(const float4*)(gA + 32);       // A(1)
    WRITE_A(fa_cur, 0)                               // auto-waits A(0)
    fa_cur = fa_nxt;
    BAR_COUNTED(1)                                   // B(0) done; A(1) in flight

    // ---- main loop: kt = 0..61 ----
    for (int kt = 0; kt < 62; ++kt) {
        const int pcur = kt & 1;
        STAGE_B((kt + 1) * 32, pcur ^ 1)             // B(k+1) [4 vmem]
        fa_nxt = *(const float4*)(gA + (kt + 2) * 32); // A(k+2) [1 vmem]
        COMPUTE_TILE(pcur)
        WRITE_A(fa_cur, pcur ^ 1)                    // A(k+1); auto vmcnt(5)
        fa_cur = fa_nxt;
        BAR_COUNTED(1)                               // B(k+1) done; A(k+2) flying
    }
    // ---- peel kt = 62 ----
    STAGE_B(63 * 32, 1)
    COMPUTE_TILE(0)
    WRITE_A(fa_cur, 1)
    BAR_COUNTED(0)
    // ---- peel kt = 63 ----
    COMPUTE_TILE(1)

#undef STAGE_B
#undef COMPUTE_TILE
#undef WRITE_A
#undef BAR_COUNTED

    // ---- fused epilogue: +bf +hid_emb, relu, dot We, reduce over n ----
    float wev[4], bfv[4];
    #pragma unroll
    for (int ni = 0; ni < 4; ++ni) {
        int n = wave * 64 + ni * 16 + c;
        wev[ni] = We[n];
        bfv[ni] = bf[n];
    }
    #pragma unroll
    for (int mi = 0; mi < 4; ++mi) {
        float part[4] = {0.f, 0.f, 0.f, 0.f};
        #pragma unroll
        for (int j = 0; j < 4; ++j) {
            int row  = mi * 16 + g * 4 + j;            // C/D: row=(lane>>4)*4+reg
            int bidx = (m0 + row) / 196;
            const float* hrow = hid_emb + (size_t)bidx * 512;
            #pragma unroll
            for (int ni = 0; ni < 4; ++ni) {
                int n = wave * 64 + ni * 16 + c;
                float v = acc[mi][ni][j] + bfv[ni] + hrow[n];
                v = fmaxf(v, 0.f);
                part[j] += v * wev[ni];
            }
        }
        #pragma unroll
        for (int j = 0; j < 4; ++j) {
            float p = part[j];
            p += __shfl_xor(p, 1, 16);
            p += __shfl_xor(p, 2, 16);
            p += __shfl_xor(p, 4, 16);
            p += __shfl_xor(p, 8, 16);
            if (c == 0) score_s[wave][mi * 16 + g * 4 + j] = p;
        }
    }
    __syncthreads();
    if (tid < 64) {
        float s = be[0];
        #pragma unroll
        for (int w = 0; w < 8; ++w) s += score_s[w][tid];
        score[m0 + tid] = s;
    }
}

// ---------------------------------------------------------------------------
// Softmax over L=196 + output[b,e] = sum_l w[l] * feature[b,l,e].
// ---------------------------------------------------------------------------
__global__ __launch_bounds__(256) void kout(
    const float* __restrict__ score, const float* __restrict__ feat,
    float* __restrict__ out_o, float* __restrict__ out_w)
{
    __shared__ float wbuf[196];
    __shared__ float red[8];
    int t    = threadIdx.x;
    int b    = blockIdx.x >> 1;
    int half = blockIdx.x & 1;
    int w    = t >> 6, lane = t & 63;

    float s = (t < 196) ? score[b * 196 + t] : -1e30f;
    float m = s;
    #pragma unroll
    for (int off = 32; off >= 1; off >>= 1) m = fmaxf(m, __shfl_xor(m, off, 64));
    if (lane == 0) red[w] = m;
    __syncthreads();
    m = fmaxf(fmaxf(red[0], red[1]), fmaxf(red[2], red[3]));
    float e = (t < 196) ? __expf(s - m) : 0.f;
    float sum = e;
    #pragma unroll
    for (int off = 32; off >= 1; off >>= 1) sum += __shfl_xor(sum, off, 64);
    if (lane == 0) red[4 + w] = sum;
    __syncthreads();
    sum = red[4] + red[5] + red[6] + red[7];
    float wt = e / sum;
    if (t < 196) {
        wbuf[t] = wt;
        if (half == 0) out_w[b * 196 + t] = wt;
    }
    __syncthreads();

    int e0 = half * 1024 + t * 4;
    float4 acc = make_float4(0.f, 0.f, 0.f, 0.f);
    const float* fb = feat + (size_t)b * L_ * ENC_ + e0;
    #pragma unroll 4
    for (int l = 0; l < 196; ++l) {
        float4 v = *(const float4*)(fb + (size_t)l * ENC_);
        float wl = wbuf[l];
        acc.x += wl * v.x; acc.y += wl * v.y; acc.z += wl * v.z; acc.w += wl * v.w;
    }
    *(float4*)(out_o + (size_t)b * ENC_ + e0) = acc;
}

extern "C" void kernel_launch(void* const* d_in, const int* in_sizes, int n_in,
                              void* d_out, int out_size, void* d_ws, size_t ws_size,
                              hipStream_t stream) {
    (void)in_sizes; (void)n_in; (void)out_size; (void)ws_size;
    const float* feature = (const float*)d_in[0];
    const float* hidden  = (const float*)d_in[1];
    const float* Wf      = (const float*)d_in[2];
    const float* bf      = (const float*)d_in[3];
    const float* Wh      = (const float*)d_in[4];
    const float* bh      = (const float*)d_in[5];
    const float* We      = (const float*)d_in[6];
    const float* be      = (const float*)d_in[7];

    char* ws = (char*)d_ws;
    short* wfbf    = (short*)ws;                               // 2 MB
    float* hid_emb = (float*)(ws + (2u << 20));                // 512 KB
    float* score   = (float*)(ws + (2u << 20) + (512u << 10)); // 200 KB

    float* out_o = (float*)d_out;                 // [256,2048]
    float* out_w = out_o + (size_t)B_ * ENC_;     // [256,196]

    kconvert<<<dim3(1024), dim3(256), 0, stream>>>(Wf, wfbf);
    khid<<<dim3(32), dim3(512), 0, stream>>>(hidden, Wh, bh, hid_emb);
    kscore<<<dim3(784), dim3(512), 0, stream>>>(feature, wfbf, bf, hid_emb, We, be, score);
    kout<<<dim3(512), dim3(256), 0, stream>>>(score, feature, (float*)d_out, out_w);
}